// Round 1
// 330.003 us; speedup vs baseline: 1.0064x; 1.0064x over previous
//
#include <hip/hip_runtime.h>

#define TV 32
#define TT 8192
#define TL 16
#define NCHAIN (TV * TL)        // 512 chains
#define CHUNK 32
#define WARM 96
#define NCHUNK (TT / CHUNK)     // 256
#define JIT 1e-6f
#define C_LOG2PI 1.837877066409345483560659472811f

// ---------------------------------------------------------------------------
// Forward Kalman filter, chunked with warm-up from the stationary prior.
// Occupancy is grid-capped at 2 waves/SIMD (512 blocks x 4 waves / 1024 SIMD),
// so amdgpu_waves_per_eu(2,2) pins the register budget at 256 VGPR and the
// batched loads can actually be kept in flight (previous build: VGPR=64 ->
// loads serialized, VALUBusy 30%, latency-bound).
// Explicit double-buffered pipeline: prefetch batch k+1 while computing k.
// Per-thread step count is always a multiple of 32 -> even number of
// 16-step batches, no tail.
// ---------------------------------------------------------------------------
#define BF 16

__global__ void __launch_bounds__(256)
__attribute__((amdgpu_waves_per_eu(2, 2)))
kf_fwd(
    const float* __restrict__ dt,    // (V, T-1)
    const float* __restrict__ y,     // (V, T, L)
    const float* __restrict__ rvar,  // (V, T, L)
    const float* __restrict__ ls,    // (L)
    const float* __restrict__ var,   // (L)
    float* __restrict__ m_fs,        // (V,L,T,2)
    float* __restrict__ P_fs,        // (V,L,T,4)
    float* __restrict__ slp)         // (V) -- pre-zeroed, atomicAdd
{
    const int tid   = blockIdx.x * 256 + threadIdx.x;
    const int chain = tid & (NCHAIN - 1);
    const int chunk = tid / NCHAIN;
    const int v = chain >> 4;
    const int l = chain & 15;

    const float lam = 1.7320508075688772f / ls[l];
    const float v0  = var[l];
    const float v1  = v0 * lam * lam;

    const int s  = chunk * CHUNK;
    const int e  = s + CHUNK;
    const int u0 = (s >= WARM) ? (s - WARM) : 0;   // multiple of 32

    const float* dtv = dt + (size_t)v * (TT - 1);
    const float* yp  = y    + (size_t)v * TT * TL + l;
    const float* rp  = rvar + (size_t)v * TT * TL + l;
    float4* mo4 = (float4*)(m_fs + (size_t)chain * TT * 2);  // [t>>1]
    float4* Po  = (float4*)(P_fs + (size_t)chain * TT * 4);

    float m0 = 0.f, m1 = 0.f;
    float P00 = v0, P01 = 0.f, P11 = v1;
    float acc = 0.f;
    float bm0 = 0.f, bm1 = 0.f;

    float ya[BF], ra[BF], da[BF];
    float yb[BF], rb[BF], db[BF];

#define FLOAD(Y, R, D, tb) {                                                  \
    _Pragma("unroll")                                                         \
    for (int j = 0; j < BF; ++j) {                                            \
        const int tt_ = (tb) + j;                                             \
        Y[j] = yp[(size_t)tt_ * TL];                                          \
        R[j] = rp[(size_t)tt_ * TL];                                          \
        D[j] = dtv[(tt_ >= 1) ? (tt_ - 1) : 0];                               \
    }                                                                         \
}

#define FCOMP(Y, R, D, tb) {                                                  \
    _Pragma("unroll")                                                         \
    for (int j = 0; j < BF; ++j) {                                            \
        const int tt_ = (tb) + j;                                             \
        const float dtc = (tt_ == 0) ? 0.f : D[j];  /* exact A=I,Q=0 at t=0 */\
        const float ldt = dtc * lam;                                          \
        const float ee  = __expf(-ldt);                                       \
        const float a11 = ee * (ldt + 1.f);                                   \
        const float a12 = ee * dtc;                                           \
        const float a21 = -ee * lam * ldt;                                    \
        const float a22 = ee * (1.f - ldt);                                   \
        const float q00 = v0 - (a11 * a11 * v0 + a12 * a12 * v1);             \
        const float q01 = -(a11 * a21 * v0 + a12 * a22 * v1);                 \
        const float q11 = v1 - (a21 * a21 * v0 + a22 * a22 * v1);             \
        const float mp0 = a11 * m0 + a12 * m1;                                \
        const float mp1 = a21 * m0 + a22 * m1;                                \
        const float ap00 = a11 * P00 + a12 * P01;                             \
        const float ap01 = a11 * P01 + a12 * P11;                             \
        const float ap10 = a21 * P00 + a22 * P01;                             \
        const float ap11 = a21 * P01 + a22 * P11;                             \
        const float pp00 = ap00 * a11 + ap01 * a12 + q00;                     \
        const float pp01 = ap00 * a21 + ap01 * a22 + q01;                     \
        const float pp11 = ap10 * a21 + ap11 * a22 + q11;                     \
        const float ssv  = pp00 + R[j];                                       \
        const float d    = Y[j] - mp0;                                        \
        const float sinv = __builtin_amdgcn_rcpf(ssv + JIT);                  \
        const float W0 = pp00 * sinv;                                         \
        const float W1 = pp01 * sinv;                                         \
        m0 = mp0 + W0 * d;                                                    \
        m1 = mp1 + W1 * d;                                                    \
        P00 = pp00 - W0 * pp00;                                               \
        P01 = pp01 - W0 * pp01;                                               \
        P11 = pp11 - W1 * pp01;                                               \
        if (tt_ >= s) {   /* batch-uniform (s, u0 multiples of 16) */         \
            acc += -0.5f * (d * d * __builtin_amdgcn_rcpf(ssv)                \
                            + __logf(ssv) + C_LOG2PI);                        \
            if ((j & 1) == 0) { bm0 = m0; bm1 = m1; }   /* tt even */         \
            else mo4[tt_ >> 1] = make_float4(bm0, bm1, m0, m1);               \
            Po[tt_] = make_float4(P00, P01, P01, P11);                        \
        }                                                                     \
    }                                                                         \
}

    // software pipeline: count = e-u0 in {32,64,96,128} -> even # of batches
    FLOAD(ya, ra, da, u0);
    for (int t = u0; t < e; t += 2 * BF) {
        FLOAD(yb, rb, db, t + BF);
        FCOMP(ya, ra, da, t);
        if (t + 2 * BF < e) FLOAD(ya, ra, da, t + 2 * BF);
        FCOMP(yb, rb, db, t + BF);
    }

    for (int mask = 8; mask >= 1; mask >>= 1)
        acc += __shfl_xor(acc, mask, 16);
    if ((threadIdx.x & 15) == 0)
        atomicAdd(&slp[v], acc);
}

// ---------------------------------------------------------------------------
// Backward RTS smoother, chunked with warm-up from the right (carry exact
// at t0==T-1). Double-buffered 8-step batches (m loaded as float4 pairs),
// amdgpu_waves_per_eu(2,2) for the register budget. Outputs buffered 4 steps
// and stored as float4.
// ---------------------------------------------------------------------------
#define BB 8

__global__ void __launch_bounds__(256)
__attribute__((amdgpu_waves_per_eu(2, 2)))
kf_bwd(
    const float* __restrict__ dt,
    const float* __restrict__ ls,
    const float* __restrict__ var,
    const float* __restrict__ m_fs,
    const float* __restrict__ P_fs,
    float* __restrict__ mZ,   // (V,L,T)
    float* __restrict__ PZ)   // (V,L,T)
{
    const int tid   = blockIdx.x * 256 + threadIdx.x;
    const int chain = tid & (NCHAIN - 1);
    const int chunk = tid / NCHAIN;
    const int v = chain >> 4;
    const int l = chain & 15;

    const float lam = 1.7320508075688772f / ls[l];
    const float v0  = var[l];
    const float v1  = v0 * lam * lam;

    const int s = chunk * CHUNK;
    const int e = s + CHUNK;
    int t0 = e - 1 + WARM;
    if (t0 > TT - 1) t0 = TT - 1;

    const float* dtv = dt + (size_t)v * (TT - 1);
    const float2* mi  = (const float2*)(m_fs + (size_t)chain * TT * 2);
    const float4* mi4 = (const float4*)(m_fs + (size_t)chain * TT * 2);
    const float4* Pi  = (const float4*)(P_fs + (size_t)chain * TT * 4);
    float* mo = mZ + (size_t)chain * TT;
    float* Po = PZ + (size_t)chain * TT;

    float2 mf2 = mi[t0];
    float4 Pf4 = Pi[t0];
    float ms0 = mf2.x, ms1 = mf2.y;
    float Ps00 = Pf4.x, Ps01 = Pf4.y, Ps11 = Pf4.w;
    if (t0 < e) { mo[t0] = ms0; Po[t0] = Ps00; }   // only when t0==e-1 (exact)

    // one smoother step; updates carry (ms*, Ps*)
    auto step = [&](float dtc, float mf0, float mf1,
                    float Pf00, float Pf01, float Pf11) {
        const float ldt = dtc * lam;
        const float ee  = __expf(-ldt);
        const float a11 = ee * (ldt + 1.f);
        const float a12 = ee * dtc;
        const float a21 = -ee * lam * ldt;
        const float a22 = ee * (1.f - ldt);
        const float q00 = v0 - (a11 * a11 * v0 + a12 * a12 * v1);
        const float q01 = -(a11 * a21 * v0 + a12 * a22 * v1);
        const float q11 = v1 - (a21 * a21 * v0 + a22 * a22 * v1);

        const float mp0 = a11 * mf0 + a12 * mf1;
        const float mp1 = a21 * mf0 + a22 * mf1;
        const float ap00 = a11 * Pf00 + a12 * Pf01;   // A @ P_f (symmetric)
        const float ap01 = a11 * Pf01 + a12 * Pf11;
        const float ap10 = a21 * Pf00 + a22 * Pf01;
        const float ap11 = a21 * Pf01 + a22 * Pf11;
        const float pp00 = ap00 * a11 + ap01 * a12 + q00;
        const float pp01 = ap00 * a21 + ap01 * a22 + q01;
        const float pp11 = ap10 * a21 + ap11 * a22 + q11;

        // G = (solve(P_p + jI, A_Pf))^T via 2x2 adjugate
        const float M00 = pp00 + JIT, M11 = pp11 + JIT;
        const float dinv = __builtin_amdgcn_rcpf(M00 * M11 - pp01 * pp01);
        const float G00 = (M11 * ap00 - pp01 * ap10) * dinv;
        const float G01 = (-pp01 * ap00 + M00 * ap10) * dinv;
        const float G10 = (M11 * ap01 - pp01 * ap11) * dinv;
        const float G11 = (-pp01 * ap01 + M00 * ap11) * dinv;

        const float dm0 = ms0 - mp0, dm1 = ms1 - mp1;
        const float nms0 = mf0 + G00 * dm0 + G01 * dm1;
        const float nms1 = mf1 + G10 * dm0 + G11 * dm1;
        const float D00 = Ps00 - pp00, D01 = Ps01 - pp01, D11 = Ps11 - pp11;
        const float gd00 = G00 * D00 + G01 * D01;
        const float gd01 = G00 * D01 + G01 * D11;
        const float gd10 = G10 * D00 + G11 * D01;
        const float gd11 = G10 * D01 + G11 * D11;
        ms0 = nms0; ms1 = nms1;
        Ps00 = Pf00 - (gd00 * G00 + gd01 * G01);
        Ps01 = Pf01 - (gd00 * G10 + gd01 * G11);
        Ps11 = Pf11 - (gd10 * G10 + gd11 * G11);
    };

    int t = t0 - 1;
    // peel until t ≡ 7 (mod 8); scalar stores (rare: warm region / tail)
    for (; t >= s && (t & 7) != 7; --t) {
        mf2 = mi[t]; Pf4 = Pi[t];
        step(dtv[t], mf2.x, mf2.y, Pf4.x, Pf4.y, Pf4.w);
        if (t < e) { mo[t] = ms0; Po[t] = Ps00; }
    }

    float b0m = 0.f, b1m = 0.f, b2m = 0.f, b3m = 0.f;
    float b0P = 0.f, b1P = 0.f, b2P = 0.f, b3P = 0.f;

    float4 Ma[BB / 2], Pa[BB]; float Da[BB];
    float4 Mb[BB / 2], Pb[BB]; float Db[BB];

// batch covers tt = tb-7 .. tb, tb ≡ 7 (mod 8).
// m loaded as 4 aligned float4 (2 timesteps each).
#define BLOAD(M, P, D, tb) {                                                  \
    const int ib_ = ((tb) - 7) >> 1;                                          \
    _Pragma("unroll")                                                         \
    for (int j = 0; j < BB / 2; ++j) M[j] = mi4[ib_ + j];                     \
    _Pragma("unroll")                                                         \
    for (int j = 0; j < BB; ++j) {                                            \
        const int tt_ = (tb) - j;                                             \
        P[j] = Pi[tt_];                                                       \
        D[j] = dtv[tt_];                                                      \
    }                                                                         \
}

#define BCOMP(M, P, D, tb) {                                                  \
    const bool wr_ = (tb) < e;   /* whole batch uniform (e mult of 32) */     \
    _Pragma("unroll")                                                         \
    for (int jj = 0; jj < BB; ++jj) {                                         \
        const int tt_ = (tb) - jj;                                            \
        const int k_  = 7 - jj;          /* index within ascending batch */   \
        const float mf0_ = (k_ & 1) ? M[k_ >> 1].z : M[k_ >> 1].x;            \
        const float mf1_ = (k_ & 1) ? M[k_ >> 1].w : M[k_ >> 1].y;            \
        step(D[jj], mf0_, mf1_, P[jj].x, P[jj].y, P[jj].w);                   \
        const int slot_ = k_ & 3;        /* == tt_ & 3, compile-time */       \
        if (slot_ == 3)      { b3m = ms0; b3P = Ps00; }                       \
        else if (slot_ == 2) { b2m = ms0; b2P = Ps00; }                       \
        else if (slot_ == 1) { b1m = ms0; b1P = Ps00; }                       \
        else {                                                                \
            b0m = ms0; b0P = Ps00;                                            \
            if (wr_) {                   /* tt_ & 3 == 0, 16B-aligned */      \
                *(float4*)(mo + tt_) = make_float4(b0m, b1m, b2m, b3m);       \
                *(float4*)(Po + tt_) = make_float4(b0P, b1P, b2P, b3P);       \
            }                                                                 \
        }                                                                     \
    }                                                                         \
}

    // software pipeline over 8-step batches; odd batch counts get a tail
    int nb = (t - s + 1) >> 3;
    if (nb > 0) {
        BLOAD(Ma, Pa, Da, t);
        for (; nb >= 2; nb -= 2) {
            BLOAD(Mb, Pb, Db, t - BB);
            BCOMP(Ma, Pa, Da, t);
            t -= BB;
            if (nb > 2) BLOAD(Ma, Pa, Da, t - BB);
            BCOMP(Mb, Pb, Db, t);
            t -= BB;
        }
        if (nb == 1) BCOMP(Ma, Pa, Da, t);
    }
}

extern "C" void kernel_launch(void* const* d_in, const int* in_sizes, int n_in,
                              void* d_out, int out_size, void* d_ws, size_t ws_size,
                              hipStream_t stream) {
    const float* dt  = (const float*)d_in[0];
    const float* y   = (const float*)d_in[1];
    const float* rv  = (const float*)d_in[2];
    const float* ls  = (const float*)d_in[3];
    const float* var = (const float*)d_in[4];

    float* out  = (float*)d_out;
    float* m_fs = out;                                    // V*L*T*2
    float* P_fs = m_fs + (size_t)NCHAIN * TT * 2;         // V*L*T*4
    float* mZ   = P_fs + (size_t)NCHAIN * TT * 4;         // V*L*T
    float* PZ   = mZ + (size_t)NCHAIN * TT;               // V*L*T
    float* slp  = PZ + (size_t)NCHAIN * TT;               // V

    hipMemsetAsync(slp, 0, TV * sizeof(float), stream);   // graph-capture safe

    const int ntask = NCHAIN * NCHUNK;                    // 131072 threads
    kf_fwd<<<ntask / 256, 256, 0, stream>>>(dt, y, rv, ls, var, m_fs, P_fs, slp);
    kf_bwd<<<ntask / 256, 256, 0, stream>>>(dt, ls, var, m_fs, P_fs, mZ, PZ);
}

// Round 2
// 308.739 us; speedup vs baseline: 1.0757x; 1.0689x over previous
//
#include <hip/hip_runtime.h>

#define TV 32
#define TT 8192
#define TL 16
#define NCHAIN (TV * TL)        // 512 chains
#define CHUNK 32
#define WARM 96
#define NCHUNK (TT / CHUNK)     // 256
#define JIT 1e-6f
#define C_LOG2PI 1.837877066409345483560659472811f
#define BF 16
#define BB 8
#define SB 8

// ---------------------------------------------------------------------------
// Forward Kalman filter, chunked with warm-up from the stationary prior.
// NEW: while filtering its output region, each thread also composes the
// backward-smoother affine map of its chunk:
//   mean:  x -> B + G*x        cov:  X -> E + S * G X G^T   (S = parity)
// from per-step (G_t, b_t, E_t) that are free byproducts of the filter
// (mf,Pf,mp,ap,pp already in registers). Maps are written coalesced to ws.
// This makes the backward pass EXACT with 1x traffic (no warm-up).
// ---------------------------------------------------------------------------
__global__ void __launch_bounds__(256)
__attribute__((amdgpu_waves_per_eu(2, 2)))
kf_fwd(
    const float* __restrict__ dt,    // (V, T-1)
    const float* __restrict__ y,     // (V, T, L)
    const float* __restrict__ rvar,  // (V, T, L)
    const float* __restrict__ ls,    // (L)
    const float* __restrict__ var,   // (L)
    float* __restrict__ m_fs,        // (V,L,T,2)
    float* __restrict__ P_fs,        // (V,L,T,4)
    float* __restrict__ slp,         // (V) -- pre-zeroed, atomicAdd
    float4* __restrict__ g4w,        // (NCHUNK, NCHAIN) Gamma
    float2* __restrict__ b2w,        // (NCHUNK, NCHAIN) B
    float4* __restrict__ e4w)        // (NCHUNK, NCHAIN) E (sym, .w pad)
{
    const int tid   = blockIdx.x * 256 + threadIdx.x;
    const int chain = tid & (NCHAIN - 1);
    const int chunk = tid / NCHAIN;     // uniform per block
    const int v = chain >> 4;
    const int l = chain & 15;

    const float lam = 1.7320508075688772f / ls[l];
    const float v0  = var[l];
    const float v1  = v0 * lam * lam;

    const int s  = chunk * CHUNK;
    const int e  = s + CHUNK;
    const int u0 = (s >= WARM) ? (s - WARM) : 0;   // multiple of 32

    const float* dtv = dt + (size_t)v * (TT - 1);
    const float* yp  = y    + (size_t)v * TT * TL + l;
    const float* rp  = rvar + (size_t)v * TT * TL + l;
    float4* mo4 = (float4*)(m_fs + (size_t)chain * TT * 2);  // [t>>1]
    float4* Po  = (float4*)(P_fs + (size_t)chain * TT * 4);

    float m0 = 0.f, m1 = 0.f;
    float P00 = v0, P01 = 0.f, P11 = v1;
    float acc = 0.f;
    float bm0 = 0.f, bm1 = 0.f;

    // composed smoother map of this chunk (identity init)
    float gam00 = 1.f, gam01 = 0.f, gam10 = 0.f, gam11 = 1.f;
    float mbc0 = 0.f, mbc1 = 0.f;
    float me00 = 0.f, me01 = 0.f, me11 = 0.f;

    float ya[BF], ra[BF], da[BF];
    float yb[BF], rb[BF], db[BF];

#define FLOAD(Y, R, D, tb) {                                                  \
    _Pragma("unroll")                                                         \
    for (int j = 0; j < BF; ++j) {                                            \
        const int tt_ = (tb) + j;                                             \
        Y[j] = yp[(size_t)tt_ * TL];                                          \
        R[j] = rp[(size_t)tt_ * TL];                                          \
        D[j] = dtv[(tt_ >= 1) ? (tt_ - 1) : 0];                               \
    }                                                                         \
}

// compose one smoother step t = tt_-1 into the running map.
// Uses PRE-update state (m0,m1,P00,P01,P11) = mf_t, Pf_t and the already
// computed mp/ap/pp of the transition t -> t+1. Sign of the E-accumulate
// is the parity of composes done so far = (j-1)&1 (compile-time).
#define MAPCOMPOSE(SGNPLUS)                                                   \
    {                                                                         \
        const float M00_ = pp00 + JIT, M11_ = pp11 + JIT;                     \
        const float dinv_ = __builtin_amdgcn_rcpf(M00_ * M11_ - pp01 * pp01); \
        const float g00 = (M11_ * ap00 - pp01 * ap10) * dinv_;                \
        const float g01 = (-pp01 * ap00 + M00_ * ap10) * dinv_;               \
        const float g10 = (M11_ * ap01 - pp01 * ap11) * dinv_;                \
        const float g11 = (-pp01 * ap01 + M00_ * ap11) * dinv_;               \
        const float bb0 = m0 - (g00 * mp0 + g01 * mp1);                       \
        const float bb1 = m1 - (g10 * mp0 + g11 * mp1);                       \
        const float gp00 = g00 * pp00 + g01 * pp01;                           \
        const float gp01 = g00 * pp01 + g01 * pp11;                           \
        const float gp10 = g10 * pp00 + g11 * pp01;                           \
        const float gp11 = g10 * pp01 + g11 * pp11;                           \
        const float ee00 = P00 + (gp00 * g00 + gp01 * g01);                   \
        const float ee01 = P01 + (gp00 * g10 + gp01 * g11);                   \
        const float ee11 = P11 + (gp10 * g10 + gp11 * g11);                   \
        mbc0 += gam00 * bb0 + gam01 * bb1;                                    \
        mbc1 += gam10 * bb0 + gam11 * bb1;                                    \
        const float u00 = gam00 * ee00 + gam01 * ee01;                        \
        const float u01 = gam00 * ee01 + gam01 * ee11;                        \
        const float u10 = gam10 * ee00 + gam11 * ee01;                        \
        const float u11 = gam10 * ee01 + gam11 * ee11;                        \
        const float r00 = u00 * gam00 + u01 * gam01;                          \
        const float r01 = u00 * gam10 + u01 * gam11;                          \
        const float r11 = u10 * gam10 + u11 * gam11;                          \
        if (SGNPLUS) { me00 += r00; me01 += r01; me11 += r11; }               \
        else         { me00 -= r00; me01 -= r01; me11 -= r11; }               \
        const float ng00 = gam00 * g00 + gam01 * g10;                         \
        const float ng01 = gam00 * g01 + gam01 * g11;                         \
        const float ng10 = gam10 * g00 + gam11 * g10;                         \
        const float ng11 = gam10 * g01 + gam11 * g11;                         \
        gam00 = ng00; gam01 = ng01; gam10 = ng10; gam11 = ng11;               \
    }

#define FCOMP(Y, R, D, tb) {                                                  \
    _Pragma("unroll")                                                         \
    for (int j = 0; j < BF; ++j) {                                            \
        const int tt_ = (tb) + j;                                             \
        const float dtc = (tt_ == 0) ? 0.f : D[j];  /* exact A=I,Q=0 at t=0 */\
        const float ldt = dtc * lam;                                          \
        const float ee  = __expf(-ldt);                                       \
        const float a11 = ee * (ldt + 1.f);                                   \
        const float a12 = ee * dtc;                                           \
        const float a21 = -ee * lam * ldt;                                    \
        const float a22 = ee * (1.f - ldt);                                   \
        const float q00 = v0 - (a11 * a11 * v0 + a12 * a12 * v1);             \
        const float q01 = -(a11 * a21 * v0 + a12 * a22 * v1);                 \
        const float q11 = v1 - (a21 * a21 * v0 + a22 * a22 * v1);             \
        const float mp0 = a11 * m0 + a12 * m1;                                \
        const float mp1 = a21 * m0 + a22 * m1;                                \
        const float ap00 = a11 * P00 + a12 * P01;                             \
        const float ap01 = a11 * P01 + a12 * P11;                             \
        const float ap10 = a21 * P00 + a22 * P01;                             \
        const float ap11 = a21 * P01 + a22 * P11;                             \
        const float pp00 = ap00 * a11 + ap01 * a12 + q00;                     \
        const float pp01 = ap00 * a21 + ap01 * a22 + q01;                     \
        const float pp11 = ap10 * a21 + ap11 * a22 + q11;                     \
        if (tt_ > s) MAPCOMPOSE((j & 1) != 0);   /* step t = tt_-1 */         \
        const float ssv  = pp00 + R[j];                                       \
        const float d    = Y[j] - mp0;                                        \
        const float sinv = __builtin_amdgcn_rcpf(ssv + JIT);                  \
        const float W0 = pp00 * sinv;                                         \
        const float W1 = pp01 * sinv;                                         \
        m0 = mp0 + W0 * d;                                                    \
        m1 = mp1 + W1 * d;                                                    \
        P00 = pp00 - W0 * pp00;                                               \
        P01 = pp01 - W0 * pp01;                                               \
        P11 = pp11 - W1 * pp01;                                               \
        if (tt_ >= s) {   /* batch-uniform (s, u0 multiples of 16) */         \
            acc += -0.5f * (d * d * __builtin_amdgcn_rcpf(ssv)                \
                            + __logf(ssv) + C_LOG2PI);                        \
            if ((j & 1) == 0) { bm0 = m0; bm1 = m1; }   /* tt even */         \
            else mo4[tt_ >> 1] = make_float4(bm0, bm1, m0, m1);               \
            Po[tt_] = make_float4(P00, P01, P01, P11);                        \
        }                                                                     \
    }                                                                         \
}

    // software pipeline: count = e-u0 in {32,64,96,128} -> even # of batches
    FLOAD(ya, ra, da, u0);
    __builtin_amdgcn_sched_barrier(0);
    for (int t = u0; t < e; t += 2 * BF) {
        FLOAD(yb, rb, db, t + BF);
        __builtin_amdgcn_sched_barrier(0);
        FCOMP(ya, ra, da, t);
        if (t + 2 * BF < e) {
            FLOAD(ya, ra, da, t + 2 * BF);
            __builtin_amdgcn_sched_barrier(0);
        }
        FCOMP(yb, rb, db, t + BF);
    }

    // epilogue: final map element, step t = e-1 (uses dt[e-1] and the
    // filtered state at e-1 now in registers). Last chunk has no step
    // t = T-1 (its 31st element was composed in-loop at tt_ = T-1).
    if (chunk != NCHUNK - 1) {
        const float dtc = dtv[e - 1];
        const float ldt = dtc * lam;
        const float ee  = __expf(-ldt);
        const float a11 = ee * (ldt + 1.f);
        const float a12 = ee * dtc;
        const float a21 = -ee * lam * ldt;
        const float a22 = ee * (1.f - ldt);
        const float q00 = v0 - (a11 * a11 * v0 + a12 * a12 * v1);
        const float q01 = -(a11 * a21 * v0 + a12 * a22 * v1);
        const float q11 = v1 - (a21 * a21 * v0 + a22 * a22 * v1);
        const float mp0 = a11 * m0 + a12 * m1;
        const float mp1 = a21 * m0 + a22 * m1;
        const float ap00 = a11 * P00 + a12 * P01;
        const float ap01 = a11 * P01 + a12 * P11;
        const float ap10 = a21 * P00 + a22 * P01;
        const float ap11 = a21 * P01 + a22 * P11;
        const float pp00 = ap00 * a11 + ap01 * a12 + q00;
        const float pp01 = ap00 * a21 + ap01 * a22 + q01;
        const float pp11 = ap10 * a21 + ap11 * a22 + q11;
        // compose count so far = 30 (even) -> '+'
        MAPCOMPOSE(1);
    }
    {
        const size_t mix = (size_t)chunk * NCHAIN + chain;   // coalesced
        g4w[mix] = make_float4(gam00, gam01, gam10, gam11);
        b2w[mix] = make_float2(mbc0, mbc1);
        e4w[mix] = make_float4(me00, me01, me11, 0.f);
    }

    for (int mask = 8; mask >= 1; mask >>= 1)
        acc += __shfl_xor(acc, mask, 16);
    if ((threadIdx.x & 15) == 0)
        atomicAdd(&slp[v], acc);
}

// ---------------------------------------------------------------------------
// Per-chain suffix scan of the chunk maps (right to left), starting from the
// exact terminal state (mf,Pf at T-1). Emits each chunk's exact incoming
// boundary state. 512 threads total; loads batched for MLP. Chunk 255 has 31
// composed steps -> its X-term sign is -1; all others (32 steps) +1.
// ---------------------------------------------------------------------------
__global__ void __launch_bounds__(256) kf_scan(
    const float* __restrict__ m_fs,
    const float* __restrict__ P_fs,
    const float4* __restrict__ g4w,
    const float2* __restrict__ b2w,
    const float4* __restrict__ e4w,
    float2* __restrict__ xmw,    // (NCHUNK, NCHAIN) incoming mean
    float4* __restrict__ xPw)    // (NCHUNK, NCHAIN) incoming cov (sym)
{
    const int c = blockIdx.x * 256 + threadIdx.x;   // chain 0..511
    const float* mt = m_fs + ((size_t)c * TT + (TT - 1)) * 2;
    const float* Pt = P_fs + ((size_t)c * TT + (TT - 1)) * 4;
    float xm0 = mt[0], xm1 = mt[1];
    float XP00 = Pt[0], XP01 = Pt[1], XP11 = Pt[3];

    float4 Gb[SB]; float2 Bb[SB]; float4 Eb[SB];
    for (int kb = NCHUNK - 1; kb >= 0; kb -= SB) {
#pragma unroll
        for (int j = 0; j < SB; ++j) {
            const size_t ix = (size_t)(kb - j) * NCHAIN + c;
            Gb[j] = g4w[ix]; Bb[j] = b2w[ix]; Eb[j] = e4w[ix];
        }
        __builtin_amdgcn_sched_barrier(0);
#pragma unroll
        for (int j = 0; j < SB; ++j) {
            const int k = kb - j;
            const size_t ix = (size_t)k * NCHAIN + c;
            xmw[ix] = make_float2(xm0, xm1);
            xPw[ix] = make_float4(XP00, XP01, XP11, 0.f);
            const float4 G = Gb[j]; const float2 B = Bb[j]; const float4 E = Eb[j];
            const float nm0 = B.x + G.x * xm0 + G.y * xm1;
            const float nm1 = B.y + G.z * xm0 + G.w * xm1;
            const float u00 = G.x * XP00 + G.y * XP01;
            const float u01 = G.x * XP01 + G.y * XP11;
            const float u10 = G.z * XP00 + G.w * XP01;
            const float u11 = G.z * XP01 + G.w * XP11;
            const float r00 = u00 * G.x + u01 * G.y;
            const float r01 = u00 * G.z + u01 * G.w;
            const float r11 = u10 * G.z + u11 * G.w;
            xm0 = nm0; xm1 = nm1;
            if (k == NCHUNK - 1) { XP00 = E.x - r00; XP01 = E.y - r01; XP11 = E.z - r11; }
            else                 { XP00 = E.x + r00; XP01 = E.y + r01; XP11 = E.z + r11; }
        }
    }
}

// ---------------------------------------------------------------------------
// Backward RTS smoother, apply-only: exact incoming state from the scan,
// 32 steps/thread, data read ONCE (no warm-up). Double-buffered 8-step
// batches with sched_barrier-pinned load issue.
// ---------------------------------------------------------------------------
__global__ void __launch_bounds__(256)
__attribute__((amdgpu_waves_per_eu(2, 2)))
kf_bwd(
    const float* __restrict__ dt,
    const float* __restrict__ ls,
    const float* __restrict__ var,
    const float* __restrict__ m_fs,
    const float* __restrict__ P_fs,
    const float2* __restrict__ xmw,
    const float4* __restrict__ xPw,
    float* __restrict__ mZ,   // (V,L,T)
    float* __restrict__ PZ)   // (V,L,T)
{
    const int tid   = blockIdx.x * 256 + threadIdx.x;
    const int chain = tid & (NCHAIN - 1);
    const int k     = tid / NCHAIN;     // uniform per block
    const int v = chain >> 4;
    const int l = chain & 15;

    const float lam = 1.7320508075688772f / ls[l];
    const float v0  = var[l];
    const float v1  = v0 * lam * lam;

    const int s = k * CHUNK;
    const int e = s + CHUNK;

    const float* dtv = dt + (size_t)v * (TT - 1);
    const float2* mi  = (const float2*)(m_fs + (size_t)chain * TT * 2);
    const float4* mi4 = (const float4*)(m_fs + (size_t)chain * TT * 2);
    const float4* Pi  = (const float4*)(P_fs + (size_t)chain * TT * 4);
    float* mo = mZ + (size_t)chain * TT;
    float* Po = PZ + (size_t)chain * TT;

    const size_t mix = (size_t)k * NCHAIN + chain;   // coalesced
    const float2 x2 = xmw[mix];
    const float4 xq = xPw[mix];
    float ms0 = x2.x, ms1 = x2.y;
    float Ps00 = xq.x, Ps01 = xq.y, Ps11 = xq.z;

    // one smoother step; updates carry (ms*, Ps*)
    auto step = [&](float dtc, float mf0, float mf1,
                    float Pf00, float Pf01, float Pf11) {
        const float ldt = dtc * lam;
        const float ee  = __expf(-ldt);
        const float a11 = ee * (ldt + 1.f);
        const float a12 = ee * dtc;
        const float a21 = -ee * lam * ldt;
        const float a22 = ee * (1.f - ldt);
        const float q00 = v0 - (a11 * a11 * v0 + a12 * a12 * v1);
        const float q01 = -(a11 * a21 * v0 + a12 * a22 * v1);
        const float q11 = v1 - (a21 * a21 * v0 + a22 * a22 * v1);

        const float mp0 = a11 * mf0 + a12 * mf1;
        const float mp1 = a21 * mf0 + a22 * mf1;
        const float ap00 = a11 * Pf00 + a12 * Pf01;   // A @ P_f (symmetric)
        const float ap01 = a11 * Pf01 + a12 * Pf11;
        const float ap10 = a21 * Pf00 + a22 * Pf01;
        const float ap11 = a21 * Pf01 + a22 * Pf11;
        const float pp00 = ap00 * a11 + ap01 * a12 + q00;
        const float pp01 = ap00 * a21 + ap01 * a22 + q01;
        const float pp11 = ap10 * a21 + ap11 * a22 + q11;

        // G = (solve(P_p + jI, A_Pf))^T via 2x2 adjugate
        const float M00 = pp00 + JIT, M11 = pp11 + JIT;
        const float dinv = __builtin_amdgcn_rcpf(M00 * M11 - pp01 * pp01);
        const float G00 = (M11 * ap00 - pp01 * ap10) * dinv;
        const float G01 = (-pp01 * ap00 + M00 * ap10) * dinv;
        const float G10 = (M11 * ap01 - pp01 * ap11) * dinv;
        const float G11 = (-pp01 * ap01 + M00 * ap11) * dinv;

        const float dm0 = ms0 - mp0, dm1 = ms1 - mp1;
        const float nms0 = mf0 + G00 * dm0 + G01 * dm1;
        const float nms1 = mf1 + G10 * dm0 + G11 * dm1;
        const float D00 = Ps00 - pp00, D01 = Ps01 - pp01, D11 = Ps11 - pp11;
        const float gd00 = G00 * D00 + G01 * D01;
        const float gd01 = G00 * D01 + G01 * D11;
        const float gd10 = G10 * D00 + G11 * D01;
        const float gd11 = G10 * D01 + G11 * D11;
        ms0 = nms0; ms1 = nms1;
        Ps00 = Pf00 - (gd00 * G00 + gd01 * G01);
        Ps01 = Pf01 - (gd00 * G10 + gd01 * G11);
        Ps11 = Pf11 - (gd10 * G10 + gd11 * G11);
    };

    int t;
    if (k == NCHUNK - 1) {
        mo[TT - 1] = ms0;       // terminal output is the incoming state
        Po[TT - 1] = Ps00;
        t = TT - 2;             // 8190
    } else {
        t = e - 1;              // ≡ 31 (mod 32) -> no peel
    }

    // peel until t ≡ 7 (mod 8); scalar stores (only last chunk: 7 steps)
    for (; t >= s && (t & 7) != 7; --t) {
        const float2 mf2 = mi[t];
        const float4 Pf4 = Pi[t];
        step(dtv[t], mf2.x, mf2.y, Pf4.x, Pf4.y, Pf4.w);
        mo[t] = ms0; Po[t] = Ps00;
    }

    float b0m = 0.f, b1m = 0.f, b2m = 0.f, b3m = 0.f;
    float b0P = 0.f, b1P = 0.f, b2P = 0.f, b3P = 0.f;

    float4 Ma[BB / 2], Pa[BB]; float Da[BB];
    float4 Mb[BB / 2], Pb[BB]; float Db[BB];

// batch covers tt = tb-7 .. tb, tb ≡ 7 (mod 8).
// m loaded as 4 aligned float4 (2 timesteps each).
#define BLOAD(M, P, D, tb) {                                                  \
    const int ib_ = ((tb) - 7) >> 1;                                          \
    _Pragma("unroll")                                                         \
    for (int j = 0; j < BB / 2; ++j) M[j] = mi4[ib_ + j];                     \
    _Pragma("unroll")                                                         \
    for (int j = 0; j < BB; ++j) {                                            \
        const int tt_ = (tb) - j;                                             \
        P[j] = Pi[tt_];                                                       \
        D[j] = dtv[tt_];                                                      \
    }                                                                         \
}

#define BCOMP(M, P, D, tb) {                                                  \
    _Pragma("unroll")                                                         \
    for (int jj = 0; jj < BB; ++jj) {                                         \
        const int tt_ = (tb) - jj;                                            \
        const int k_  = 7 - jj;          /* index within ascending batch */   \
        const float mf0_ = (k_ & 1) ? M[k_ >> 1].z : M[k_ >> 1].x;            \
        const float mf1_ = (k_ & 1) ? M[k_ >> 1].w : M[k_ >> 1].y;            \
        step(D[jj], mf0_, mf1_, P[jj].x, P[jj].y, P[jj].w);                   \
        const int slot_ = k_ & 3;        /* == tt_ & 3, compile-time */       \
        if (slot_ == 3)      { b3m = ms0; b3P = Ps00; }                       \
        else if (slot_ == 2) { b2m = ms0; b2P = Ps00; }                       \
        else if (slot_ == 1) { b1m = ms0; b1P = Ps00; }                       \
        else {                                                                \
            b0m = ms0; b0P = Ps00;                                            \
            {                            /* tt_ & 3 == 0, 16B-aligned */      \
                *(float4*)(mo + tt_) = make_float4(b0m, b1m, b2m, b3m);       \
                *(float4*)(Po + tt_) = make_float4(b0P, b1P, b2P, b3P);       \
            }                                                                 \
        }                                                                     \
    }                                                                         \
}

    // software pipeline over 8-step batches; odd batch counts get a tail
    int nb = (t - s + 1) >> 3;      // 4 (k<255) or 3 (k==255)
    if (nb > 0) {
        BLOAD(Ma, Pa, Da, t);
        __builtin_amdgcn_sched_barrier(0);
        for (; nb >= 2; nb -= 2) {
            BLOAD(Mb, Pb, Db, t - BB);
            __builtin_amdgcn_sched_barrier(0);
            BCOMP(Ma, Pa, Da, t);
            t -= BB;
            if (nb > 2) {
                BLOAD(Ma, Pa, Da, t - BB);
                __builtin_amdgcn_sched_barrier(0);
            }
            BCOMP(Mb, Pb, Db, t);
            t -= BB;
        }
        if (nb == 1) BCOMP(Ma, Pa, Da, t);
    }
}

extern "C" void kernel_launch(void* const* d_in, const int* in_sizes, int n_in,
                              void* d_out, int out_size, void* d_ws, size_t ws_size,
                              hipStream_t stream) {
    const float* dt  = (const float*)d_in[0];
    const float* y   = (const float*)d_in[1];
    const float* rv  = (const float*)d_in[2];
    const float* ls  = (const float*)d_in[3];
    const float* var = (const float*)d_in[4];

    float* out  = (float*)d_out;
    float* m_fs = out;                                    // V*L*T*2
    float* P_fs = m_fs + (size_t)NCHAIN * TT * 2;         // V*L*T*4
    float* mZ   = P_fs + (size_t)NCHAIN * TT * 4;         // V*L*T
    float* PZ   = mZ + (size_t)NCHAIN * TT;               // V*L*T
    float* slp  = PZ + (size_t)NCHAIN * TT;               // V

    // workspace: chunk maps + scan output, 64 B per (chunk,chain) = 8 MiB
    float4* g4w = (float4*)d_ws;
    float4* e4w = g4w + (size_t)NCHUNK * NCHAIN;
    float4* xPw = e4w + (size_t)NCHUNK * NCHAIN;
    float2* b2w = (float2*)(xPw + (size_t)NCHUNK * NCHAIN);
    float2* xmw = b2w + (size_t)NCHUNK * NCHAIN;

    hipMemsetAsync(slp, 0, TV * sizeof(float), stream);   // graph-capture safe

    const int ntask = NCHAIN * NCHUNK;                    // 131072 threads
    kf_fwd<<<ntask / 256, 256, 0, stream>>>(dt, y, rv, ls, var, m_fs, P_fs, slp,
                                            g4w, b2w, e4w);
    kf_scan<<<NCHAIN / 256, 256, 0, stream>>>(m_fs, P_fs, g4w, b2w, e4w, xmw, xPw);
    kf_bwd<<<ntask / 256, 256, 0, stream>>>(dt, ls, var, m_fs, P_fs, xmw, xPw, mZ, PZ);
}